// Round 6
// baseline (315.493 us; speedup 1.0000x reference)
//
#include <hip/hip_runtime.h>
#include <math.h>

#define B_   2
#define SQ_  2048
#define SK_  2048
#define DM_  1024
#define H_   16
#define D_   64

typedef __attribute__((ext_vector_type(8))) short bf16x8;
typedef __attribute__((ext_vector_type(4))) float f32x4;
typedef unsigned int u32;

// fp32 -> bf16 RNE
__device__ __forceinline__ short f2bf(float f) {
    union { float f; unsigned u; } v; v.f = f;
    unsigned r = v.u + 0x7FFFu + ((v.u >> 16) & 1u);
    return (short)(r >> 16);
}
// pack two fp32 -> two bf16 (round-half-up) in one u32
__device__ __forceinline__ u32 pk2bf(float x, float y) {
    union { float f; u32 u; } a, b; a.f = x; b.f = y;
    return ((a.u + 0x8000u) >> 16) | ((b.u + 0x8000u) & 0xFFFF0000u);
}

__device__ __forceinline__ void gll16(const void* g, void* l) {
    __builtin_amdgcn_global_load_lds(
        (const __attribute__((address_space(1))) u32*)g,
        (__attribute__((address_space(3))) u32*)l, 16, 0, 0);
}

// ---------------------------------------------------------------------------
// prep_x: fp32 -> bf16 convert of x (y=0) and x2 (y=1)
// ---------------------------------------------------------------------------
__global__ __launch_bounds__(256) void prep_x_kernel(
    const float* __restrict__ x, const float* __restrict__ x2,
    short* __restrict__ xb, short* __restrict__ x2b)
{
    const float* src = blockIdx.y ? x2 : x;
    short* dst       = blockIdx.y ? x2b : xb;
    int i = blockIdx.x * 256 + threadIdx.x;
    float4 v = ((const float4*)src)[i];
    short4 s;
    s.x = f2bf(v.x); s.y = f2bf(v.y); s.z = f2bf(v.z); s.w = f2bf(v.w);
    ((short4*)dst)[i] = s;
}

// ---------------------------------------------------------------------------
// prep_w: z=0..2 -> Wq/Wk/Wv [16,1024,64] f32 -> WT[h*64+d][m] bf16 (transposed)
//         z=3    -> Wo fp32 -> bf16 convert
// ---------------------------------------------------------------------------
__global__ __launch_bounds__(256) void prep_w_kernel(
    const float* __restrict__ Wq, const float* __restrict__ Wk,
    const float* __restrict__ Wv, const float* __restrict__ Wo,
    short* __restrict__ WqT, short* __restrict__ WkT,
    short* __restrict__ WvT, short* __restrict__ Wob)
{
    const int t = threadIdx.x;
    const int z = blockIdx.z;
    if (z == 3) {
        int base = (blockIdx.y * 16 + blockIdx.x) * 1024 + t;   // float4 units
        #pragma unroll
        for (int j = 0; j < 4; j++) {
            int i = base + j * 256;
            float4 v = ((const float4*)Wo)[i];
            short4 s;
            s.x = f2bf(v.x); s.y = f2bf(v.y); s.z = f2bf(v.z); s.w = f2bf(v.w);
            ((short4*)Wob)[i] = s;
        }
        return;
    }
    const float* W = (z == 0) ? Wq : (z == 1) ? Wk : Wv;
    short* WT      = (z == 0) ? WqT : (z == 1) ? WkT : WvT;
    const int h  = blockIdx.y;
    const int m0 = blockIdx.x * 64;
    __shared__ short Ls[64][68];

    #pragma unroll
    for (int it = 0; it < 4; it++) {
        int lin = it * 256 + t;         // float4 units, 1024 total
        int m = lin >> 4, d4 = lin & 15;
        float4 v = *(const float4*)&W[((long)h * DM_ + m0 + m) * D_ + d4 * 4];
        short4 s;
        s.x = f2bf(v.x); s.y = f2bf(v.y); s.z = f2bf(v.z); s.w = f2bf(v.w);
        *(short4*)&Ls[m][d4 * 4] = s;
    }
    __syncthreads();
    #pragma unroll
    for (int it = 0; it < 2; it++) {
        int d = (t >> 3) + it * 32, scol = t & 7;
        bf16x8 vv;
        #pragma unroll
        for (int j = 0; j < 8; j++) vv[j] = Ls[scol * 8 + j][d];
        *(bf16x8*)&WT[((long)h * 64 + d) * DM_ + m0 + scol * 8] = vv;
    }
}

// ---------------------------------------------------------------------------
// Vb [4096,1024] bf16 -> VT [32][64][2048] : VT[bh][d][s]=Vb[b*2048+s][h*64+d]
// ---------------------------------------------------------------------------
__global__ __launch_bounds__(256) void vtrans_kernel(
    const short* __restrict__ Vb, short* __restrict__ VT)
{
    const int bh = blockIdx.y;
    const int b  = bh >> 4, h = bh & 15;
    const int s0 = blockIdx.x * 64;
    const int t  = threadIdx.x;
    __shared__ short Ls[64][68];

    #pragma unroll
    for (int it = 0; it < 2; it++) {
        int lin = it * 256 + t;
        int s = lin >> 3, c8 = lin & 7;
        bf16x8 v = *(const bf16x8*)&Vb[((long)(b * 2048 + s0 + s)) * 1024 + h * 64 + c8 * 8];
        short4 a, c;
        a.x = v[0]; a.y = v[1]; a.z = v[2]; a.w = v[3];
        c.x = v[4]; c.y = v[5]; c.z = v[6]; c.w = v[7];
        *(short4*)&Ls[s][c8 * 8]     = a;
        *(short4*)&Ls[s][c8 * 8 + 4] = c;
    }
    __syncthreads();
    #pragma unroll
    for (int it = 0; it < 2; it++) {
        int d = (t >> 3) + it * 32, scol = t & 7;
        bf16x8 vv;
        #pragma unroll
        for (int j = 0; j < 8; j++) vv[j] = Ls[scol * 8 + j][d];
        *(bf16x8*)&VT[((long)bh * 64 + d) * 2048 + s0 + scol * 8] = vv;
    }
}

// ---------------------------------------------------------------------------
// m97-style bf16 MFMA GEMM (128x128 tile, BK=64, gll16 + XOR swizzle).
// oscale folds the attention scale * log2(e) into Q.
// ---------------------------------------------------------------------------
template <bool BF16_OUT>
__device__ __forceinline__ void gemm_core(
    const short* __restrict__ A, const short* __restrict__ Bw,
    const float* __restrict__ bias, void* __restrict__ outp,
    int r0, int n0, float oscale)
{
    __shared__ short As[128 * 64];
    __shared__ short Bs[128 * 64];

    const int t    = threadIdx.x;
    const int w    = t >> 6;
    const int ln   = t & 63;
    const int l15  = ln & 15;
    const int quad = ln >> 4;
    const int wr   = w >> 1;
    const int wc   = w & 1;

    f32x4 acc[4][4];
    #pragma unroll
    for (int i = 0; i < 4; i++)
        #pragma unroll
        for (int j = 0; j < 4; j++) acc[i][j] = (f32x4){0.f, 0.f, 0.f, 0.f};

    const int srow = ln >> 3;
    const int sc   = (ln & 7) ^ srow;
    const int rsw  = l15 & 7;

    for (int k0 = 0; k0 < 1024; k0 += 64) {
        __syncthreads();
        #pragma unroll
        for (int j = 0; j < 4; j++) {
            int q   = w * 4 + j;
            int row = q * 8 + srow;
            gll16(A  + ((long)(r0 + row) << 10) + k0 + sc * 8, As + q * 512);
            gll16(Bw + ((long)(n0 + row) << 10) + k0 + sc * 8, Bs + q * 512);
        }
        __syncthreads();
        #pragma unroll
        for (int kh = 0; kh < 2; kh++) {
            bf16x8 af[4], bfr[4];
            #pragma unroll
            for (int i = 0; i < 4; i++) {
                int ra = wr * 64 + i * 16 + l15;
                int rb = wc * 64 + i * 16 + l15;
                int pc = ((kh * 4 + quad) ^ rsw) * 8;
                af[i]  = *(const bf16x8*)&As[ra * 64 + pc];
                bfr[i] = *(const bf16x8*)&Bs[rb * 64 + pc];
            }
            #pragma unroll
            for (int i = 0; i < 4; i++)
                #pragma unroll
                for (int j = 0; j < 4; j++)
                    acc[i][j] = __builtin_amdgcn_mfma_f32_16x16x32_bf16(
                        af[i], bfr[j], acc[i][j], 0, 0, 0);
        }
    }

    #pragma unroll
    for (int j = 0; j < 4; j++) {
        int col = n0 + wc * 64 + j * 16 + l15;
        float bv = bias[col];
        #pragma unroll
        for (int i = 0; i < 4; i++) {
            int rowb = r0 + wr * 64 + i * 16 + quad * 4;
            #pragma unroll
            for (int r = 0; r < 4; r++) {
                float v = (acc[i][j][r] + bv) * oscale;
                if (BF16_OUT)
                    ((short*)outp)[(long)(rowb + r) * 1024 + col] = f2bf(v);
                else
                    ((float*)outp)[(long)(rowb + r) * 1024 + col] = v;
            }
        }
    }
}

// Q scale: 1/sqrt(64) * log2(e)  (flash uses exp2 directly)
#define QSCALE 0.180336880977f

__global__ __launch_bounds__(256) void gemm_qkv_kernel(
    const short* __restrict__ x2b, const short* __restrict__ xb,
    const short* __restrict__ WqT, const short* __restrict__ WkT,
    const short* __restrict__ WvT,
    const float* __restrict__ bq, const float* __restrict__ bk,
    const float* __restrict__ bv,
    short* __restrict__ Qb, short* __restrict__ Kb, short* __restrict__ Vb)
{
    const int z = blockIdx.z;
    const short* A    = (z == 0) ? x2b : xb;
    const short* Bw   = (z == 0) ? WqT : (z == 1) ? WkT : WvT;
    const float* bias = (z == 0) ? bq  : (z == 1) ? bk  : bv;
    short* outp       = (z == 0) ? Qb  : (z == 1) ? Kb  : Vb;
    const float scl   = (z == 0) ? QSCALE : 1.0f;
    gemm_core<true>(A, Bw, bias, outp, blockIdx.x * 128, blockIdx.y * 128, scl);
}

__global__ __launch_bounds__(256) void gemm_out_kernel(
    const short* __restrict__ A, const short* __restrict__ Wob,
    const float* __restrict__ bo, float* __restrict__ out)
{
    gemm_core<false>(A, Wob, bo, out, blockIdx.x * 128, blockIdx.y * 128, 1.0f);
}

// ---------------------------------------------------------------------------
// MFMA flash attention v4.
// Block = 256 threads / 4 waves, 16 q-rows per wave (round-4 occupancy regime).
// S computed TRANSPOSED (A=K, B=Q): lane l15 = q, kpos = 16kt+4quad+r ->
// P packs to one ds_write_b64 per kt (round-5's verified swizzle).
// V-fragments load DIRECTLY from global VT[bh][d][s] (exact B-frag layout),
// served by L2/L3 -> no V LDS stage. Only K is staged (gll16 + XOR swizzle).
// Static softmax (exp2, Q pre-scaled by 0.125*log2e); row-sum l via ones-MFMA.
// Q,K bf16 [b,s,h*64+d]; VT bf16 [bh][64][2048]; O bf16 [b,s,1024].
// ---------------------------------------------------------------------------
__global__ __launch_bounds__(256) void flash_kernel(
    const short* __restrict__ Q, const short* __restrict__ K,
    const short* __restrict__ VT, short* __restrict__ O)
{
    const int t    = threadIdx.x;
    const int wave = t >> 6;
    const int ln   = t & 63;
    const int l15  = ln & 15;
    const int quad = ln >> 4;
    const int bh = blockIdx.y;
    const int b  = bh >> 4;
    const int h  = bh & 15;
    const int q0 = blockIdx.x * 64;
    const int wq = q0 + wave * 16;          // this wave's first q row

    __shared__ short Ks[64 * 64];           // [kpos][d], XOR-swizzled chunks
    __shared__ short Ps[4][16 * 64];        // per-wave P, XOR-swizzled u64 slots

    const int srow = ln >> 3;               // row within 8-row staging chunk
    const int sc   = (ln & 7) ^ srow;       // swizzled source chunk (16B)
    const int rsw  = l15 & 7;               // read-side swizzle key

    // Q B-fragments (pre-scaled by 0.125*log2e): lane l15 = q, k = quad*8+j
    bf16x8 aQ0, aQ1;
    {
        const short* Qp = Q + ((long)(b * SQ_ + wq + l15)) * 1024 + h * 64 + quad * 8;
        aQ0 = *(const bf16x8*)(Qp);
        aQ1 = *(const bf16x8*)(Qp + 32);
    }

    bf16x8 ones;
    #pragma unroll
    for (int j = 0; j < 8; j++) ones[j] = (short)0x3F80;   // bf16 1.0

    f32x4 o_acc[4];
    #pragma unroll
    for (int i = 0; i < 4; i++) o_acc[i] = (f32x4){0.f, 0.f, 0.f, 0.f};
    f32x4 l_acc = (f32x4){0.f, 0.f, 0.f, 0.f};

    const short* Kbase = K  + ((long)b * SK_) * 1024 + h * 64;
    const short* Vbase = VT + (long)bh * D_ * SK_;

    for (int k0 = 0; k0 < SK_; k0 += 64) {
        __syncthreads();                     // Ks frag reads of prev iter done
        #pragma unroll
        for (int it = 0; it < 2; ++it) {
            int qq  = wave * 2 + it;         // 8-row group 0..7
            int row = qq * 8 + srow;         // kpos
            gll16(Kbase + (long)(k0 + row) * 1024 + sc * 8, Ks + qq * 512);
        }
        // V B-frags straight from global while the K DMA is in flight
        bf16x8 bv[4][2];
        #pragma unroll
        for (int dt = 0; dt < 4; dt++) {
            const short* vp = Vbase + (long)(dt * 16 + l15) * SK_ + k0 + quad * 8;
            bv[dt][0] = *(const bf16x8*)(vp);
            bv[dt][1] = *(const bf16x8*)(vp + 32);
        }
        __syncthreads();                     // K staged

        // --- S^T[kpos][q] = K·Q^T : A = K rows from LDS, B = Q regs ---
        f32x4 st[4];
        #pragma unroll
        for (int kt = 0; kt < 4; kt++) {
            const short* kr = &Ks[(kt * 16 + l15) * 64];
            bf16x8 ka0 = *(const bf16x8*)&kr[((quad    ) ^ rsw) * 8];
            bf16x8 ka1 = *(const bf16x8*)&kr[((quad + 4) ^ rsw) * 8];
            f32x4 z = (f32x4){0.f, 0.f, 0.f, 0.f};
            z = __builtin_amdgcn_mfma_f32_16x16x32_bf16(ka0, aQ0, z, 0, 0, 0);
            z = __builtin_amdgcn_mfma_f32_16x16x32_bf16(ka1, aQ1, z, 0, 0, 0);
            st[kt] = z;
        }

        // --- P = exp2(S^T): lane q=l15, kpos=16kt+4quad+{0..3} ->
        //     one packed ds_write_b64 per kt ---
        short* pr = &Ps[wave][l15 * 64];
        #pragma unroll
        for (int kt = 0; kt < 4; kt++) {
            float p0 = exp2f(st[kt][0]);
            float p1 = exp2f(st[kt][1]);
            float p2 = exp2f(st[kt][2]);
            float p3 = exp2f(st[kt][3]);
            int phys = (4 * kt + quad) ^ (rsw << 1);   // u64-slot swizzle
            uint2 wv; wv.x = pk2bf(p0, p1); wv.y = pk2bf(p2, p3);
            *(uint2*)&pr[phys * 4] = wv;
        }

        // --- P A-frags (lane m=q=l15, k contiguous) ; l += P·1 ; O += P·V ---
        bf16x8 aP0 = *(const bf16x8*)&pr[((quad    ) ^ rsw) * 8];
        bf16x8 aP1 = *(const bf16x8*)&pr[((quad + 4) ^ rsw) * 8];
        l_acc = __builtin_amdgcn_mfma_f32_16x16x32_bf16(aP0, ones, l_acc, 0, 0, 0);
        l_acc = __builtin_amdgcn_mfma_f32_16x16x32_bf16(aP1, ones, l_acc, 0, 0, 0);
        #pragma unroll
        for (int dt = 0; dt < 4; dt++) {
            o_acc[dt] = __builtin_amdgcn_mfma_f32_16x16x32_bf16(aP0, bv[dt][0], o_acc[dt], 0, 0, 0);
            o_acc[dt] = __builtin_amdgcn_mfma_f32_16x16x32_bf16(aP1, bv[dt][1], o_acc[dt], 0, 0, 0);
        }
    }

    // --- epilogue: normalize, write head-concat bf16 (col l15 = d) ---
    #pragma unroll
    for (int r = 0; r < 4; r++) {
        float inv = 1.0f / l_acc[r];
        long row = (long)b * SQ_ + wq + quad * 4 + r;
        short* Op = O + row * 1024 + h * 64 + l15;
        #pragma unroll
        for (int dt = 0; dt < 4; dt++)
            Op[dt * 16] = f2bf(o_acc[dt][r] * inv);
    }
}

extern "C" void kernel_launch(void* const* d_in, const int* in_sizes, int n_in,
                              void* d_out, int out_size, void* d_ws, size_t ws_size,
                              hipStream_t stream) {
    const float* x  = (const float*)d_in[0];
    const float* x2 = (const float*)d_in[1];
    const float* Wq = (const float*)d_in[2];
    const float* bq = (const float*)d_in[3];
    const float* Wk = (const float*)d_in[4];
    const float* bk = (const float*)d_in[5];
    const float* Wv = (const float*)d_in[6];
    const float* bv = (const float*)d_in[7];
    const float* Wo = (const float*)d_in[8];
    const float* bo = (const float*)d_in[9];
    float* out = (float*)d_out;

    const size_t nAct = (size_t)B_ * SK_ * DM_;    // 4,194,304
    const size_t nW   = (size_t)DM_ * DM_;         // 1,048,576
    short* bufA = (short*)d_ws;        // xb, later VT
    short* bufB = bufA + nAct;         // x2b, later O (bf16)
    short* Qb   = bufB + nAct;
    short* Kb   = Qb + nAct;
    short* Vb   = Kb + nAct;
    short* WqT  = Vb + nAct;
    short* WkT  = WqT + nW;
    short* WvT  = WkT + nW;
    short* Wob  = WvT + nW;

    prep_x_kernel<<<dim3((int)(nAct / 4 / 256), 2), 256, 0, stream>>>(x, x2, bufA, bufB);
    prep_w_kernel<<<dim3(16, 16, 4), 256, 0, stream>>>(Wq, Wk, Wv, Wo, WqT, WkT, WvT, Wob);

    gemm_qkv_kernel<<<dim3(32, 8, 3), 256, 0, stream>>>(
        bufB, bufA, WqT, WkT, WvT, bq, bk, bv, Qb, Kb, Vb);

    vtrans_kernel<<<dim3(32, 32), 256, 0, stream>>>(Vb, bufA);       // bufA = VT
    flash_kernel<<<dim3(32, 32), 256, 0, stream>>>(Qb, Kb, bufA, bufB); // bufB = O
    gemm_out_kernel<<<dim3(32, 8), 256, 0, stream>>>(bufB, Wob, bo, out);
}

// Round 7
// 251.083 us; speedup vs baseline: 1.2565x; 1.2565x over previous
//
#include <hip/hip_runtime.h>
#include <math.h>

#define B_   2
#define SQ_  2048
#define SK_  2048
#define DM_  1024
#define H_   16
#define D_   64

typedef __attribute__((ext_vector_type(8))) short bf16x8;
typedef __attribute__((ext_vector_type(4))) float f32x4;
typedef unsigned int u32;

// fp32 -> bf16 RNE
__device__ __forceinline__ short f2bf(float f) {
    union { float f; unsigned u; } v; v.f = f;
    unsigned r = v.u + 0x7FFFu + ((v.u >> 16) & 1u);
    return (short)(r >> 16);
}
// pack two fp32 -> two bf16 (round-half-up) in one u32
__device__ __forceinline__ u32 pk2bf(float x, float y) {
    union { float f; u32 u; } a, b; a.f = x; b.f = y;
    return ((a.u + 0x8000u) >> 16) | ((b.u + 0x8000u) & 0xFFFF0000u);
}

__device__ __forceinline__ void gll16(const void* g, void* l) {
    __builtin_amdgcn_global_load_lds(
        (const __attribute__((address_space(1))) u32*)g,
        (__attribute__((address_space(3))) u32*)l, 16, 0, 0);
}

// ---------------------------------------------------------------------------
// prep_x: fp32 -> bf16 convert of x (y=0) and x2 (y=1)
// ---------------------------------------------------------------------------
__global__ __launch_bounds__(256) void prep_x_kernel(
    const float* __restrict__ x, const float* __restrict__ x2,
    short* __restrict__ xb, short* __restrict__ x2b)
{
    const float* src = blockIdx.y ? x2 : x;
    short* dst       = blockIdx.y ? x2b : xb;
    int i = blockIdx.x * 256 + threadIdx.x;
    float4 v = ((const float4*)src)[i];
    short4 s;
    s.x = f2bf(v.x); s.y = f2bf(v.y); s.z = f2bf(v.z); s.w = f2bf(v.w);
    ((short4*)dst)[i] = s;
}

// ---------------------------------------------------------------------------
// prep_w: z=0..2 -> Wq/Wk/Wv [16,1024,64] f32 -> WT[h*64+d][m] bf16 (transposed)
//         z=3    -> Wo fp32 -> bf16 convert
// ---------------------------------------------------------------------------
__global__ __launch_bounds__(256) void prep_w_kernel(
    const float* __restrict__ Wq, const float* __restrict__ Wk,
    const float* __restrict__ Wv, const float* __restrict__ Wo,
    short* __restrict__ WqT, short* __restrict__ WkT,
    short* __restrict__ WvT, short* __restrict__ Wob)
{
    const int t = threadIdx.x;
    const int z = blockIdx.z;
    if (z == 3) {
        int base = (blockIdx.y * 16 + blockIdx.x) * 1024 + t;   // float4 units
        #pragma unroll
        for (int j = 0; j < 4; j++) {
            int i = base + j * 256;
            float4 v = ((const float4*)Wo)[i];
            short4 s;
            s.x = f2bf(v.x); s.y = f2bf(v.y); s.z = f2bf(v.z); s.w = f2bf(v.w);
            ((short4*)Wob)[i] = s;
        }
        return;
    }
    const float* W = (z == 0) ? Wq : (z == 1) ? Wk : Wv;
    short* WT      = (z == 0) ? WqT : (z == 1) ? WkT : WvT;
    const int h  = blockIdx.y;
    const int m0 = blockIdx.x * 64;
    __shared__ short Ls[64][68];

    #pragma unroll
    for (int it = 0; it < 4; it++) {
        int lin = it * 256 + t;         // float4 units, 1024 total
        int m = lin >> 4, d4 = lin & 15;
        float4 v = *(const float4*)&W[((long)h * DM_ + m0 + m) * D_ + d4 * 4];
        short4 s;
        s.x = f2bf(v.x); s.y = f2bf(v.y); s.z = f2bf(v.z); s.w = f2bf(v.w);
        *(short4*)&Ls[m][d4 * 4] = s;
    }
    __syncthreads();
    #pragma unroll
    for (int it = 0; it < 2; it++) {
        int d = (t >> 3) + it * 32, scol = t & 7;
        bf16x8 vv;
        #pragma unroll
        for (int j = 0; j < 8; j++) vv[j] = Ls[scol * 8 + j][d];
        *(bf16x8*)&WT[((long)h * 64 + d) * DM_ + m0 + scol * 8] = vv;
    }
}

// ---------------------------------------------------------------------------
// Vb [4096,1024] bf16 -> VT [32][64][2048] : VT[bh][d][s]=Vb[b*2048+s][h*64+d]
// ---------------------------------------------------------------------------
__global__ __launch_bounds__(256) void vtrans_kernel(
    const short* __restrict__ Vb, short* __restrict__ VT)
{
    const int bh = blockIdx.y;
    const int b  = bh >> 4, h = bh & 15;
    const int s0 = blockIdx.x * 64;
    const int t  = threadIdx.x;
    __shared__ short Ls[64][68];

    #pragma unroll
    for (int it = 0; it < 2; it++) {
        int lin = it * 256 + t;
        int s = lin >> 3, c8 = lin & 7;
        bf16x8 v = *(const bf16x8*)&Vb[((long)(b * 2048 + s0 + s)) * 1024 + h * 64 + c8 * 8];
        short4 a, c;
        a.x = v[0]; a.y = v[1]; a.z = v[2]; a.w = v[3];
        c.x = v[4]; c.y = v[5]; c.z = v[6]; c.w = v[7];
        *(short4*)&Ls[s][c8 * 8]     = a;
        *(short4*)&Ls[s][c8 * 8 + 4] = c;
    }
    __syncthreads();
    #pragma unroll
    for (int it = 0; it < 2; it++) {
        int d = (t >> 3) + it * 32, scol = t & 7;
        bf16x8 vv;
        #pragma unroll
        for (int j = 0; j < 8; j++) vv[j] = Ls[scol * 8 + j][d];
        *(bf16x8*)&VT[((long)bh * 64 + d) * 2048 + s0 + scol * 8] = vv;
    }
}

// ---------------------------------------------------------------------------
// m97-style bf16 MFMA GEMM (128x128 tile, BK=64, gll16 + XOR swizzle).
// oscale folds the attention scale * log2(e) into Q.
// ---------------------------------------------------------------------------
template <bool BF16_OUT>
__device__ __forceinline__ void gemm_core(
    const short* __restrict__ A, const short* __restrict__ Bw,
    const float* __restrict__ bias, void* __restrict__ outp,
    int r0, int n0, float oscale)
{
    __shared__ short As[128 * 64];
    __shared__ short Bs[128 * 64];

    const int t    = threadIdx.x;
    const int w    = t >> 6;
    const int ln   = t & 63;
    const int l15  = ln & 15;
    const int quad = ln >> 4;
    const int wr   = w >> 1;
    const int wc   = w & 1;

    f32x4 acc[4][4];
    #pragma unroll
    for (int i = 0; i < 4; i++)
        #pragma unroll
        for (int j = 0; j < 4; j++) acc[i][j] = (f32x4){0.f, 0.f, 0.f, 0.f};

    const int srow = ln >> 3;
    const int sc   = (ln & 7) ^ srow;
    const int rsw  = l15 & 7;

    for (int k0 = 0; k0 < 1024; k0 += 64) {
        __syncthreads();
        #pragma unroll
        for (int j = 0; j < 4; j++) {
            int q   = w * 4 + j;
            int row = q * 8 + srow;
            gll16(A  + ((long)(r0 + row) << 10) + k0 + sc * 8, As + q * 512);
            gll16(Bw + ((long)(n0 + row) << 10) + k0 + sc * 8, Bs + q * 512);
        }
        __syncthreads();
        #pragma unroll
        for (int kh = 0; kh < 2; kh++) {
            bf16x8 af[4], bfr[4];
            #pragma unroll
            for (int i = 0; i < 4; i++) {
                int ra = wr * 64 + i * 16 + l15;
                int rb = wc * 64 + i * 16 + l15;
                int pc = ((kh * 4 + quad) ^ rsw) * 8;
                af[i]  = *(const bf16x8*)&As[ra * 64 + pc];
                bfr[i] = *(const bf16x8*)&Bs[rb * 64 + pc];
            }
            #pragma unroll
            for (int i = 0; i < 4; i++)
                #pragma unroll
                for (int j = 0; j < 4; j++)
                    acc[i][j] = __builtin_amdgcn_mfma_f32_16x16x32_bf16(
                        af[i], bfr[j], acc[i][j], 0, 0, 0);
        }
    }

    #pragma unroll
    for (int j = 0; j < 4; j++) {
        int col = n0 + wc * 64 + j * 16 + l15;
        float bv = bias[col];
        #pragma unroll
        for (int i = 0; i < 4; i++) {
            int rowb = r0 + wr * 64 + i * 16 + quad * 4;
            #pragma unroll
            for (int r = 0; r < 4; r++) {
                float v = (acc[i][j][r] + bv) * oscale;
                if (BF16_OUT)
                    ((short*)outp)[(long)(rowb + r) * 1024 + col] = f2bf(v);
                else
                    ((float*)outp)[(long)(rowb + r) * 1024 + col] = v;
            }
        }
    }
}

// Q scale: 1/sqrt(64) * log2(e)  (flash uses exp2 directly)
#define QSCALE 0.180336880977f

__global__ __launch_bounds__(256) void gemm_qkv_kernel(
    const short* __restrict__ x2b, const short* __restrict__ xb,
    const short* __restrict__ WqT, const short* __restrict__ WkT,
    const short* __restrict__ WvT,
    const float* __restrict__ bq, const float* __restrict__ bk,
    const float* __restrict__ bv,
    short* __restrict__ Qb, short* __restrict__ Kb, short* __restrict__ Vb)
{
    const int z = blockIdx.z;
    const short* A    = (z == 0) ? x2b : xb;
    const short* Bw   = (z == 0) ? WqT : (z == 1) ? WkT : WvT;
    const float* bias = (z == 0) ? bq  : (z == 1) ? bk  : bv;
    short* outp       = (z == 0) ? Qb  : (z == 1) ? Kb  : Vb;
    const float scl   = (z == 0) ? QSCALE : 1.0f;
    gemm_core<true>(A, Bw, bias, outp, blockIdx.x * 128, blockIdx.y * 128, scl);
}

__global__ __launch_bounds__(256) void gemm_out_kernel(
    const short* __restrict__ A, const short* __restrict__ Wob,
    const float* __restrict__ bo, float* __restrict__ out)
{
    gemm_core<false>(A, Wob, bo, out, blockIdx.x * 128, blockIdx.y * 128, 1.0f);
}

// ---------------------------------------------------------------------------
// MFMA flash attention v5.
// Block = 256 threads / 4 waves; each wave owns 32 q-rows (2 q-subtiles).
// K AND V staged in LDS via gll16 + XOR swizzle (round-4 staging: nothing
// else shares the vmcnt drain at the barrier).
// S computed TRANSPOSED (A=K frags from LDS, B=Q regs): lane l15 = q,
// kpos = 16kt+4quad+r -> P packs to one ds_write_b64 per (qt,kt)
// (round-5's correctness-verified swizzle).
// K/V fragments are read from LDS ONCE and serve both q-subtiles.
// Static softmax (exp2, Q pre-scaled by 0.125*log2e); row-sum via ones-MFMA.
// Q,K bf16 [b,s,h*64+d]; VT bf16 [bh][64][2048]; O bf16 [b,s,1024].
// ---------------------------------------------------------------------------
__global__ __launch_bounds__(256) void flash_kernel(
    const short* __restrict__ Q, const short* __restrict__ K,
    const short* __restrict__ VT, short* __restrict__ O)
{
    const int t    = threadIdx.x;
    const int wave = t >> 6;
    const int ln   = t & 63;
    const int l15  = ln & 15;
    const int quad = ln >> 4;
    const int bh = blockIdx.y;
    const int b  = bh >> 4;
    const int h  = bh & 15;
    const int q0 = blockIdx.x * 128;
    const int wq = q0 + wave * 32;          // this wave's first q row

    __shared__ short Ks[64 * 64];           // [kpos][d], XOR-swizzled chunks
    __shared__ short Vs[64 * 64];           // [d][kpos], XOR-swizzled chunks
    __shared__ short Ps[4][32 * 64];        // per-wave P, XOR-swizzled u64 slots

    const int srow = ln >> 3;               // row within 8-row staging chunk
    const int sc   = (ln & 7) ^ srow;       // swizzled source chunk (16B)
    const int rsw  = l15 & 7;               // read-side swizzle key

    // Q B-fragments (pre-scaled by 0.125*log2e): lane l15 = q, k = quad*8+j
    bf16x8 aQ[2][2];
    #pragma unroll
    for (int qt = 0; qt < 2; qt++) {
        const short* Qp = Q + ((long)(b * SQ_ + wq + qt * 16 + l15)) * 1024
                            + h * 64 + quad * 8;
        aQ[qt][0] = *(const bf16x8*)(Qp);
        aQ[qt][1] = *(const bf16x8*)(Qp + 32);
    }

    bf16x8 ones;
    #pragma unroll
    for (int j = 0; j < 8; j++) ones[j] = (short)0x3F80;   // bf16 1.0

    f32x4 o_acc[2][4];
    #pragma unroll
    for (int qt = 0; qt < 2; qt++)
        #pragma unroll
        for (int i = 0; i < 4; i++) o_acc[qt][i] = (f32x4){0.f, 0.f, 0.f, 0.f};
    f32x4 l_acc[2] = {(f32x4){0.f,0.f,0.f,0.f}, (f32x4){0.f,0.f,0.f,0.f}};

    const short* Kbase = K  + ((long)b * SK_) * 1024 + h * 64;
    const short* Vbase = VT + (long)bh * D_ * SK_;

    for (int k0 = 0; k0 < SK_; k0 += 64) {
        __syncthreads();                     // prev iter's frag reads done
        #pragma unroll
        for (int it = 0; it < 2; ++it) {
            int qq  = wave * 2 + it;         // 8-row group 0..7
            int row = qq * 8 + srow;         // kpos (K) / d (V)
            gll16(Kbase + (long)(k0 + row) * 1024 + sc * 8, Ks + qq * 512);
            gll16(Vbase + (long)row * 2048 + k0 + sc * 8,   Vs + qq * 512);
        }
        __syncthreads();                     // tiles staged

        // --- S^T[kpos][q] = K·Q^T : K A-frags read ONCE, serve both qt ---
        f32x4 st[2][4];
        #pragma unroll
        for (int kt = 0; kt < 4; kt++) {
            const short* kr = &Ks[(kt * 16 + l15) * 64];
            bf16x8 ka0 = *(const bf16x8*)&kr[((quad    ) ^ rsw) * 8];
            bf16x8 ka1 = *(const bf16x8*)&kr[((quad + 4) ^ rsw) * 8];
            #pragma unroll
            for (int qt = 0; qt < 2; qt++) {
                f32x4 z = (f32x4){0.f, 0.f, 0.f, 0.f};
                z = __builtin_amdgcn_mfma_f32_16x16x32_bf16(ka0, aQ[qt][0], z, 0, 0, 0);
                z = __builtin_amdgcn_mfma_f32_16x16x32_bf16(ka1, aQ[qt][1], z, 0, 0, 0);
                st[qt][kt] = z;
            }
        }

        // --- P = exp2(S^T): lane q=l15(+16qt), kpos=16kt+4quad+{0..3} ->
        //     one packed ds_write_b64 per (qt,kt) ---
        #pragma unroll
        for (int qt = 0; qt < 2; qt++) {
            short* pr = &Ps[wave][(qt * 16 + l15) * 64];
            #pragma unroll
            for (int kt = 0; kt < 4; kt++) {
                float p0 = exp2f(st[qt][kt][0]);
                float p1 = exp2f(st[qt][kt][1]);
                float p2 = exp2f(st[qt][kt][2]);
                float p3 = exp2f(st[qt][kt][3]);
                int phys = (4 * kt + quad) ^ (rsw << 1);   // u64-slot swizzle
                uint2 wv; wv.x = pk2bf(p0, p1); wv.y = pk2bf(p2, p3);
                *(uint2*)&pr[phys * 4] = wv;
            }
        }

        // --- P A-frags ; l += P·1 ---
        bf16x8 aP[2][2];
        #pragma unroll
        for (int qt = 0; qt < 2; qt++) {
            const short* pr = &Ps[wave][(qt * 16 + l15) * 64];
            aP[qt][0] = *(const bf16x8*)&pr[((quad    ) ^ rsw) * 8];
            aP[qt][1] = *(const bf16x8*)&pr[((quad + 4) ^ rsw) * 8];
            l_acc[qt] = __builtin_amdgcn_mfma_f32_16x16x32_bf16(aP[qt][0], ones, l_acc[qt], 0, 0, 0);
            l_acc[qt] = __builtin_amdgcn_mfma_f32_16x16x32_bf16(aP[qt][1], ones, l_acc[qt], 0, 0, 0);
        }

        // --- O += P·V : V B-frags read ONCE, serve both qt ---
        #pragma unroll
        for (int dt = 0; dt < 4; dt++) {
            const short* vr = &Vs[(dt * 16 + l15) * 64];
            bf16x8 bv0 = *(const bf16x8*)&vr[((quad    ) ^ rsw) * 8];
            bf16x8 bv1 = *(const bf16x8*)&vr[((quad + 4) ^ rsw) * 8];
            #pragma unroll
            for (int qt = 0; qt < 2; qt++) {
                o_acc[qt][dt] = __builtin_amdgcn_mfma_f32_16x16x32_bf16(aP[qt][0], bv0, o_acc[qt][dt], 0, 0, 0);
                o_acc[qt][dt] = __builtin_amdgcn_mfma_f32_16x16x32_bf16(aP[qt][1], bv1, o_acc[qt][dt], 0, 0, 0);
            }
        }
    }

    // --- epilogue: normalize, write head-concat bf16 (col l15 = d) ---
    #pragma unroll
    for (int qt = 0; qt < 2; qt++) {
        #pragma unroll
        for (int r = 0; r < 4; r++) {
            float inv = 1.0f / l_acc[qt][r];
            long row = (long)b * SQ_ + wq + qt * 16 + quad * 4 + r;
            short* Op = O + row * 1024 + h * 64 + l15;
            #pragma unroll
            for (int dt = 0; dt < 4; dt++)
                Op[dt * 16] = f2bf(o_acc[qt][dt][r] * inv);
        }
    }
}

extern "C" void kernel_launch(void* const* d_in, const int* in_sizes, int n_in,
                              void* d_out, int out_size, void* d_ws, size_t ws_size,
                              hipStream_t stream) {
    const float* x  = (const float*)d_in[0];
    const float* x2 = (const float*)d_in[1];
    const float* Wq = (const float*)d_in[2];
    const float* bq = (const float*)d_in[3];
    const float* Wk = (const float*)d_in[4];
    const float* bk = (const float*)d_in[5];
    const float* Wv = (const float*)d_in[6];
    const float* bv = (const float*)d_in[7];
    const float* Wo = (const float*)d_in[8];
    const float* bo = (const float*)d_in[9];
    float* out = (float*)d_out;

    const size_t nAct = (size_t)B_ * SK_ * DM_;    // 4,194,304
    const size_t nW   = (size_t)DM_ * DM_;         // 1,048,576
    short* bufA = (short*)d_ws;        // xb, later VT
    short* bufB = bufA + nAct;         // x2b, later O (bf16)
    short* Qb   = bufB + nAct;
    short* Kb   = Qb + nAct;
    short* Vb   = Kb + nAct;
    short* WqT  = Vb + nAct;
    short* WkT  = WqT + nW;
    short* WvT  = WkT + nW;
    short* Wob  = WvT + nW;

    prep_x_kernel<<<dim3((int)(nAct / 4 / 256), 2), 256, 0, stream>>>(x, x2, bufA, bufB);
    prep_w_kernel<<<dim3(16, 16, 4), 256, 0, stream>>>(Wq, Wk, Wv, Wo, WqT, WkT, WvT, Wob);

    gemm_qkv_kernel<<<dim3(32, 8, 3), 256, 0, stream>>>(
        bufB, bufA, WqT, WkT, WvT, bq, bk, bv, Qb, Kb, Vb);

    vtrans_kernel<<<dim3(32, 32), 256, 0, stream>>>(Vb, bufA);       // bufA = VT
    flash_kernel<<<dim3(16, 32), 256, 0, stream>>>(Qb, Kb, bufA, bufB); // bufB = O
    gemm_out_kernel<<<dim3(32, 8), 256, 0, stream>>>(bufB, Wob, bo, out);
}

// Round 8
// 243.339 us; speedup vs baseline: 1.2965x; 1.0318x over previous
//
#include <hip/hip_runtime.h>
#include <math.h>

#define B_   2
#define SQ_  2048
#define SK_  2048
#define DM_  1024
#define H_   16
#define D_   64

typedef __attribute__((ext_vector_type(8))) short bf16x8;
typedef __attribute__((ext_vector_type(4))) float f32x4;
typedef unsigned int u32;

// fp32 -> bf16 RNE
__device__ __forceinline__ short f2bf(float f) {
    union { float f; unsigned u; } v; v.f = f;
    unsigned r = v.u + 0x7FFFu + ((v.u >> 16) & 1u);
    return (short)(r >> 16);
}
// pack two fp32 -> two bf16 (round-half-up) in one u32
__device__ __forceinline__ u32 pk2bf(float x, float y) {
    union { float f; u32 u; } a, b; a.f = x; b.f = y;
    return ((a.u + 0x8000u) >> 16) | ((b.u + 0x8000u) & 0xFFFF0000u);
}

__device__ __forceinline__ void gll16(const void* g, void* l) {
    __builtin_amdgcn_global_load_lds(
        (const __attribute__((address_space(1))) u32*)g,
        (__attribute__((address_space(3))) u32*)l, 16, 0, 0);
}

// ---------------------------------------------------------------------------
// prep: z=0..2 -> Wq/Wk/Wv [16,1024,64] f32 -> WT[h*64+d][m] bf16 (transposed)
//       z=3    -> Wo fp32 -> bf16 convert
//       z=4,5  -> x / x2 fp32 -> bf16 convert
// ---------------------------------------------------------------------------
__global__ __launch_bounds__(256) void prep_kernel(
    const float* __restrict__ Wq, const float* __restrict__ Wk,
    const float* __restrict__ Wv, const float* __restrict__ Wo,
    const float* __restrict__ x,  const float* __restrict__ x2,
    short* __restrict__ WqT, short* __restrict__ WkT,
    short* __restrict__ WvT, short* __restrict__ Wob,
    short* __restrict__ xb,  short* __restrict__ x2b)
{
    const int t = threadIdx.x;
    const int z = blockIdx.z;
    if (z >= 3) {
        const float* src = (z == 3) ? Wo : (z == 4) ? x : x2;
        short* dst       = (z == 3) ? Wob : (z == 4) ? xb : x2b;
        int nloop = (z == 3) ? 4 : 16;              // Wo: 1M floats; x: 4M
        int bid = blockIdx.y * 16 + blockIdx.x;     // 0..255
        #pragma unroll 4
        for (int j = 0; j < nloop; j++) {
            int i = bid * (nloop * 256) + j * 256 + t;   // float4 units
            float4 v = ((const float4*)src)[i];
            short4 s;
            s.x = f2bf(v.x); s.y = f2bf(v.y); s.z = f2bf(v.z); s.w = f2bf(v.w);
            ((short4*)dst)[i] = s;
        }
        return;
    }
    const float* W = (z == 0) ? Wq : (z == 1) ? Wk : Wv;
    short* WT      = (z == 0) ? WqT : (z == 1) ? WkT : WvT;
    const int h  = blockIdx.y;
    const int m0 = blockIdx.x * 64;
    __shared__ short Ls[64][68];

    #pragma unroll
    for (int it = 0; it < 4; it++) {
        int lin = it * 256 + t;         // float4 units, 1024 total
        int m = lin >> 4, d4 = lin & 15;
        float4 v = *(const float4*)&W[((long)h * DM_ + m0 + m) * D_ + d4 * 4];
        short4 s;
        s.x = f2bf(v.x); s.y = f2bf(v.y); s.z = f2bf(v.z); s.w = f2bf(v.w);
        *(short4*)&Ls[m][d4 * 4] = s;
    }
    __syncthreads();
    #pragma unroll
    for (int it = 0; it < 2; it++) {
        int d = (t >> 3) + it * 32, scol = t & 7;
        bf16x8 vv;
        #pragma unroll
        for (int j = 0; j < 8; j++) vv[j] = Ls[scol * 8 + j][d];
        *(bf16x8*)&WT[((long)h * 64 + d) * DM_ + m0 + scol * 8] = vv;
    }
}

// ---------------------------------------------------------------------------
// Vb [4096,1024] bf16 -> VT [32][64][2048] : VT[bh][d][s]=Vb[b*2048+s][h*64+d]
// ---------------------------------------------------------------------------
__global__ __launch_bounds__(256) void vtrans_kernel(
    const short* __restrict__ Vb, short* __restrict__ VT)
{
    const int bh = blockIdx.y;
    const int b  = bh >> 4, h = bh & 15;
    const int s0 = blockIdx.x * 64;
    const int t  = threadIdx.x;
    __shared__ short Ls[64][68];

    #pragma unroll
    for (int it = 0; it < 2; it++) {
        int lin = it * 256 + t;
        int s = lin >> 3, c8 = lin & 7;
        bf16x8 v = *(const bf16x8*)&Vb[((long)(b * 2048 + s0 + s)) * 1024 + h * 64 + c8 * 8];
        short4 a, c;
        a.x = v[0]; a.y = v[1]; a.z = v[2]; a.w = v[3];
        c.x = v[4]; c.y = v[5]; c.z = v[6]; c.w = v[7];
        *(short4*)&Ls[s][c8 * 8]     = a;
        *(short4*)&Ls[s][c8 * 8 + 4] = c;
    }
    __syncthreads();
    #pragma unroll
    for (int it = 0; it < 2; it++) {
        int d = (t >> 3) + it * 32, scol = t & 7;
        bf16x8 vv;
        #pragma unroll
        for (int j = 0; j < 8; j++) vv[j] = Ls[scol * 8 + j][d];
        *(bf16x8*)&VT[((long)bh * 64 + d) * 2048 + s0 + scol * 8] = vv;
    }
}

// ---------------------------------------------------------------------------
// m97-style bf16 MFMA GEMM (128x128 tile, BK=64, gll16 + XOR swizzle).
// oscale folds the attention scale * log2(e) into Q.
// ---------------------------------------------------------------------------
template <bool BF16_OUT>
__device__ __forceinline__ void gemm_core(
    const short* __restrict__ A, const short* __restrict__ Bw,
    const float* __restrict__ bias, void* __restrict__ outp,
    int r0, int n0, float oscale)
{
    __shared__ short As[128 * 64];
    __shared__ short Bs[128 * 64];

    const int t    = threadIdx.x;
    const int w    = t >> 6;
    const int ln   = t & 63;
    const int l15  = ln & 15;
    const int quad = ln >> 4;
    const int wr   = w >> 1;
    const int wc   = w & 1;

    f32x4 acc[4][4];
    #pragma unroll
    for (int i = 0; i < 4; i++)
        #pragma unroll
        for (int j = 0; j < 4; j++) acc[i][j] = (f32x4){0.f, 0.f, 0.f, 0.f};

    const int srow = ln >> 3;
    const int sc   = (ln & 7) ^ srow;
    const int rsw  = l15 & 7;

    for (int k0 = 0; k0 < 1024; k0 += 64) {
        __syncthreads();
        #pragma unroll
        for (int j = 0; j < 4; j++) {
            int q   = w * 4 + j;
            int row = q * 8 + srow;
            gll16(A  + ((long)(r0 + row) << 10) + k0 + sc * 8, As + q * 512);
            gll16(Bw + ((long)(n0 + row) << 10) + k0 + sc * 8, Bs + q * 512);
        }
        __syncthreads();
        #pragma unroll
        for (int kh = 0; kh < 2; kh++) {
            bf16x8 af[4], bfr[4];
            #pragma unroll
            for (int i = 0; i < 4; i++) {
                int ra = wr * 64 + i * 16 + l15;
                int rb = wc * 64 + i * 16 + l15;
                int pc = ((kh * 4 + quad) ^ rsw) * 8;
                af[i]  = *(const bf16x8*)&As[ra * 64 + pc];
                bfr[i] = *(const bf16x8*)&Bs[rb * 64 + pc];
            }
            #pragma unroll
            for (int i = 0; i < 4; i++)
                #pragma unroll
                for (int j = 0; j < 4; j++)
                    acc[i][j] = __builtin_amdgcn_mfma_f32_16x16x32_bf16(
                        af[i], bfr[j], acc[i][j], 0, 0, 0);
        }
    }

    #pragma unroll
    for (int j = 0; j < 4; j++) {
        int col = n0 + wc * 64 + j * 16 + l15;
        float bv = bias[col];
        #pragma unroll
        for (int i = 0; i < 4; i++) {
            int rowb = r0 + wr * 64 + i * 16 + quad * 4;
            #pragma unroll
            for (int r = 0; r < 4; r++) {
                float v = (acc[i][j][r] + bv) * oscale;
                if (BF16_OUT)
                    ((short*)outp)[(long)(rowb + r) * 1024 + col] = f2bf(v);
                else
                    ((float*)outp)[(long)(rowb + r) * 1024 + col] = v;
            }
        }
    }
}

// Q scale: 1/sqrt(64) * log2(e)  (flash uses exp2 directly)
#define QSCALE 0.180336880977f

__global__ __launch_bounds__(256) void gemm_qkv_kernel(
    const short* __restrict__ x2b, const short* __restrict__ xb,
    const short* __restrict__ WqT, const short* __restrict__ WkT,
    const short* __restrict__ WvT,
    const float* __restrict__ bq, const float* __restrict__ bk,
    const float* __restrict__ bv,
    short* __restrict__ Qb, short* __restrict__ Kb, short* __restrict__ Vb)
{
    const int z = blockIdx.z;
    const short* A    = (z == 0) ? x2b : xb;
    const short* Bw   = (z == 0) ? WqT : (z == 1) ? WkT : WvT;
    const float* bias = (z == 0) ? bq  : (z == 1) ? bk  : bv;
    short* outp       = (z == 0) ? Qb  : (z == 1) ? Kb  : Vb;
    const float scl   = (z == 0) ? QSCALE : 1.0f;
    gemm_core<true>(A, Bw, bias, outp, blockIdx.x * 128, blockIdx.y * 128, scl);
}

__global__ __launch_bounds__(256) void gemm_out_kernel(
    const short* __restrict__ A, const short* __restrict__ Wob,
    const float* __restrict__ bo, float* __restrict__ out)
{
    gemm_core<false>(A, Wob, bo, out, blockIdx.x * 128, blockIdx.y * 128, 1.0f);
}

// ---------------------------------------------------------------------------
// MFMA flash attention v6 = round-4 config + S^T/b64 P round-trip.
// Block = 256 threads / 4 waves, 16 q-rows per wave; grid (32,32)=1024 blocks
// (4 blocks/CU — the verified latency-hiding regime; VGPR ~55).
// K AND V staged via gll16 + XOR swizzle (nothing else on the vmcnt drain).
// S computed TRANSPOSED (A=K frags, B=Q regs): lane l15 = q,
// kpos = 16kt+4quad+r -> P packs to one ds_write_b64 per kt
// (round-5's correctness-verified pair-preserving swizzle).
// Static softmax (exp2, Q pre-scaled 0.125*log2e); row-sum via ones-MFMA.
// Q,K bf16 [b,s,h*64+d]; VT bf16 [bh][64][2048]; O bf16 [b,s,1024].
// ---------------------------------------------------------------------------
__global__ __launch_bounds__(256) void flash_kernel(
    const short* __restrict__ Q, const short* __restrict__ K,
    const short* __restrict__ VT, short* __restrict__ O)
{
    const int t    = threadIdx.x;
    const int wave = t >> 6;
    const int ln   = t & 63;
    const int l15  = ln & 15;
    const int quad = ln >> 4;
    const int bh = blockIdx.y;
    const int b  = bh >> 4;
    const int h  = bh & 15;
    const int q0 = blockIdx.x * 64;
    const int wq = q0 + wave * 16;          // this wave's first q row

    __shared__ short Ks[64 * 64];           // [kpos][d], XOR-swizzled chunks
    __shared__ short Vs[64 * 64];           // [d][kpos], XOR-swizzled chunks
    __shared__ short Ps[4][16 * 64];        // per-wave P[q][kpos], swizzled u64

    const int srow = ln >> 3;               // row within 8-row staging chunk
    const int sc   = (ln & 7) ^ srow;       // swizzled source chunk (16B)
    const int rsw  = l15 & 7;               // read-side swizzle key

    // Q B-fragments (pre-scaled by 0.125*log2e): lane l15 = q, k = quad*8+j
    bf16x8 aQ0, aQ1;
    {
        const short* Qp = Q + ((long)(b * SQ_ + wq + l15)) * 1024 + h * 64 + quad * 8;
        aQ0 = *(const bf16x8*)(Qp);
        aQ1 = *(const bf16x8*)(Qp + 32);
    }

    bf16x8 ones;
    #pragma unroll
    for (int j = 0; j < 8; j++) ones[j] = (short)0x3F80;   // bf16 1.0

    f32x4 o_acc[4];
    #pragma unroll
    for (int i = 0; i < 4; i++) o_acc[i] = (f32x4){0.f, 0.f, 0.f, 0.f};
    f32x4 l_acc = (f32x4){0.f, 0.f, 0.f, 0.f};

    const short* Kbase = K  + ((long)b * SK_) * 1024 + h * 64;
    const short* Vbase = VT + (long)bh * D_ * SK_;

    for (int k0 = 0; k0 < SK_; k0 += 64) {
        __syncthreads();                     // prev iter's frag reads done
        #pragma unroll
        for (int it = 0; it < 2; ++it) {
            int qq  = wave * 2 + it;         // 8-row group 0..7
            int row = qq * 8 + srow;         // kpos (K) / d (V)
            gll16(Kbase + (long)(k0 + row) * 1024 + sc * 8, Ks + qq * 512);
            gll16(Vbase + (long)row * 2048 + k0 + sc * 8,   Vs + qq * 512);
        }
        __syncthreads();                     // tiles staged

        // --- S^T[kpos][q] = K·Q^T : A = K frags from LDS, B = Q regs ---
        f32x4 st[4];
        #pragma unroll
        for (int kt = 0; kt < 4; kt++) {
            const short* kr = &Ks[(kt * 16 + l15) * 64];
            bf16x8 ka0 = *(const bf16x8*)&kr[((quad    ) ^ rsw) * 8];
            bf16x8 ka1 = *(const bf16x8*)&kr[((quad + 4) ^ rsw) * 8];
            f32x4 z = (f32x4){0.f, 0.f, 0.f, 0.f};
            z = __builtin_amdgcn_mfma_f32_16x16x32_bf16(ka0, aQ0, z, 0, 0, 0);
            z = __builtin_amdgcn_mfma_f32_16x16x32_bf16(ka1, aQ1, z, 0, 0, 0);
            st[kt] = z;
        }

        // --- P = exp2(S^T): lane q=l15, kpos=16kt+4quad+{0..3} ->
        //     one packed ds_write_b64 per kt (pair-preserving swizzle) ---
        short* pr = &Ps[wave][l15 * 64];
        #pragma unroll
        for (int kt = 0; kt < 4; kt++) {
            float p0 = exp2f(st[kt][0]);
            float p1 = exp2f(st[kt][1]);
            float p2 = exp2f(st[kt][2]);
            float p3 = exp2f(st[kt][3]);
            int phys = (4 * kt + quad) ^ (rsw << 1);   // u64-slot swizzle
            uint2 wv; wv.x = pk2bf(p0, p1); wv.y = pk2bf(p2, p3);
            *(uint2*)&pr[phys * 4] = wv;
        }

        // --- P A-frags (lane m=q=l15, k contiguous) ; l += P·1 ; O += P·V ---
        bf16x8 aP0 = *(const bf16x8*)&pr[((quad    ) ^ rsw) * 8];
        bf16x8 aP1 = *(const bf16x8*)&pr[((quad + 4) ^ rsw) * 8];
        l_acc = __builtin_amdgcn_mfma_f32_16x16x32_bf16(aP0, ones, l_acc, 0, 0, 0);
        l_acc = __builtin_amdgcn_mfma_f32_16x16x32_bf16(aP1, ones, l_acc, 0, 0, 0);
        #pragma unroll
        for (int dt = 0; dt < 4; dt++) {
            const short* vr = &Vs[(dt * 16 + l15) * 64];
            bf16x8 bv0 = *(const bf16x8*)&vr[((quad    ) ^ rsw) * 8];
            bf16x8 bv1 = *(const bf16x8*)&vr[((quad + 4) ^ rsw) * 8];
            o_acc[dt] = __builtin_amdgcn_mfma_f32_16x16x32_bf16(aP0, bv0, o_acc[dt], 0, 0, 0);
            o_acc[dt] = __builtin_amdgcn_mfma_f32_16x16x32_bf16(aP1, bv1, o_acc[dt], 0, 0, 0);
        }
    }

    // --- epilogue: normalize, write head-concat bf16 (col l15 = d) ---
    #pragma unroll
    for (int r = 0; r < 4; r++) {
        float inv = 1.0f / l_acc[r];
        long row = (long)b * SQ_ + wq + quad * 4 + r;
        short* Op = O + row * 1024 + h * 64 + l15;
        #pragma unroll
        for (int dt = 0; dt < 4; dt++)
            Op[dt * 16] = f2bf(o_acc[dt][r] * inv);
    }
}

extern "C" void kernel_launch(void* const* d_in, const int* in_sizes, int n_in,
                              void* d_out, int out_size, void* d_ws, size_t ws_size,
                              hipStream_t stream) {
    const float* x  = (const float*)d_in[0];
    const float* x2 = (const float*)d_in[1];
    const float* Wq = (const float*)d_in[2];
    const float* bq = (const float*)d_in[3];
    const float* Wk = (const float*)d_in[4];
    const float* bk = (const float*)d_in[5];
    const float* Wv = (const float*)d_in[6];
    const float* bv = (const float*)d_in[7];
    const float* Wo = (const float*)d_in[8];
    const float* bo = (const float*)d_in[9];
    float* out = (float*)d_out;

    const size_t nAct = (size_t)B_ * SK_ * DM_;    // 4,194,304
    const size_t nW   = (size_t)DM_ * DM_;         // 1,048,576
    short* bufA = (short*)d_ws;        // xb, later VT
    short* bufB = bufA + nAct;         // x2b, later O (bf16)
    short* Qb   = bufB + nAct;
    short* Kb   = Qb + nAct;
    short* Vb   = Kb + nAct;
    short* WqT  = Vb + nAct;
    short* WkT  = WqT + nW;
    short* WvT  = WkT + nW;
    short* Wob  = WvT + nW;

    prep_kernel<<<dim3(16, 16, 6), 256, 0, stream>>>(
        Wq, Wk, Wv, Wo, x, x2, WqT, WkT, WvT, Wob, bufA, bufB);

    gemm_qkv_kernel<<<dim3(32, 8, 3), 256, 0, stream>>>(
        bufB, bufA, WqT, WkT, WvT, bq, bk, bv, Qb, Kb, Vb);

    vtrans_kernel<<<dim3(32, 32), 256, 0, stream>>>(Vb, bufA);       // bufA = VT
    flash_kernel<<<dim3(32, 32), 256, 0, stream>>>(Qb, Kb, bufA, bufB); // bufB = O
    gemm_out_kernel<<<dim3(32, 8), 256, 0, stream>>>(bufB, Wob, bo, out);
}

// Round 9
// 231.071 us; speedup vs baseline: 1.3653x; 1.0531x over previous
//
#include <hip/hip_runtime.h>
#include <math.h>

#define B_   2
#define SQ_  2048
#define SK_  2048
#define DM_  1024
#define H_   16
#define D_   64

typedef __attribute__((ext_vector_type(8))) short bf16x8;
typedef __attribute__((ext_vector_type(4))) float f32x4;
typedef unsigned int u32;

// fp32 -> bf16 RNE
__device__ __forceinline__ short f2bf(float f) {
    union { float f; unsigned u; } v; v.f = f;
    unsigned r = v.u + 0x7FFFu + ((v.u >> 16) & 1u);
    return (short)(r >> 16);
}
// pack two fp32 -> two bf16 (round-half-up) in one u32
__device__ __forceinline__ u32 pk2bf(float x, float y) {
    union { float f; u32 u; } a, b; a.f = x; b.f = y;
    return ((a.u + 0x8000u) >> 16) | ((b.u + 0x8000u) & 0xFFFF0000u);
}

__device__ __forceinline__ void gll16(const void* g, void* l) {
    __builtin_amdgcn_global_load_lds(
        (const __attribute__((address_space(1))) u32*)g,
        (__attribute__((address_space(3))) u32*)l, 16, 0, 0);
}

// ---------------------------------------------------------------------------
// prep: z=0..2 -> Wq/Wk/Wv [16,1024,64] f32 -> WT[h*64+d][m] bf16 (transposed)
//       z=3    -> Wo fp32 -> bf16 convert
//       z=4,5  -> x / x2 fp32 -> bf16 convert
// ---------------------------------------------------------------------------
__global__ __launch_bounds__(256) void prep_kernel(
    const float* __restrict__ Wq, const float* __restrict__ Wk,
    const float* __restrict__ Wv, const float* __restrict__ Wo,
    const float* __restrict__ x,  const float* __restrict__ x2,
    short* __restrict__ WqT, short* __restrict__ WkT,
    short* __restrict__ WvT, short* __restrict__ Wob,
    short* __restrict__ xb,  short* __restrict__ x2b)
{
    const int t = threadIdx.x;
    const int z = blockIdx.z;
    if (z >= 3) {
        const float* src = (z == 3) ? Wo : (z == 4) ? x : x2;
        short* dst       = (z == 3) ? Wob : (z == 4) ? xb : x2b;
        int nloop = (z == 3) ? 4 : 16;              // Wo: 1M floats; x: 4M
        int bid = blockIdx.y * 16 + blockIdx.x;     // 0..255
        #pragma unroll 4
        for (int j = 0; j < nloop; j++) {
            int i = bid * (nloop * 256) + j * 256 + t;   // float4 units
            float4 v = ((const float4*)src)[i];
            short4 s;
            s.x = f2bf(v.x); s.y = f2bf(v.y); s.z = f2bf(v.z); s.w = f2bf(v.w);
            ((short4*)dst)[i] = s;
        }
        return;
    }
    const float* W = (z == 0) ? Wq : (z == 1) ? Wk : Wv;
    short* WT      = (z == 0) ? WqT : (z == 1) ? WkT : WvT;
    const int h  = blockIdx.y;
    const int m0 = blockIdx.x * 64;
    __shared__ short Ls[64][68];

    #pragma unroll
    for (int it = 0; it < 4; it++) {
        int lin = it * 256 + t;         // float4 units, 1024 total
        int m = lin >> 4, d4 = lin & 15;
        float4 v = *(const float4*)&W[((long)h * DM_ + m0 + m) * D_ + d4 * 4];
        short4 s;
        s.x = f2bf(v.x); s.y = f2bf(v.y); s.z = f2bf(v.z); s.w = f2bf(v.w);
        *(short4*)&Ls[m][d4 * 4] = s;
    }
    __syncthreads();
    #pragma unroll
    for (int it = 0; it < 2; it++) {
        int d = (t >> 3) + it * 32, scol = t & 7;
        bf16x8 vv;
        #pragma unroll
        for (int j = 0; j < 8; j++) vv[j] = Ls[scol * 8 + j][d];
        *(bf16x8*)&WT[((long)h * 64 + d) * DM_ + m0 + scol * 8] = vv;
    }
}

// ---------------------------------------------------------------------------
// Vb [4096,1024] bf16 -> VT [32][64][2048] : VT[bh][d][s]=Vb[b*2048+s][h*64+d]
// ---------------------------------------------------------------------------
__global__ __launch_bounds__(256) void vtrans_kernel(
    const short* __restrict__ Vb, short* __restrict__ VT)
{
    const int bh = blockIdx.y;
    const int b  = bh >> 4, h = bh & 15;
    const int s0 = blockIdx.x * 64;
    const int t  = threadIdx.x;
    __shared__ short Ls[64][68];

    #pragma unroll
    for (int it = 0; it < 2; it++) {
        int lin = it * 256 + t;
        int s = lin >> 3, c8 = lin & 7;
        bf16x8 v = *(const bf16x8*)&Vb[((long)(b * 2048 + s0 + s)) * 1024 + h * 64 + c8 * 8];
        short4 a, c;
        a.x = v[0]; a.y = v[1]; a.z = v[2]; a.w = v[3];
        c.x = v[4]; c.y = v[5]; c.z = v[6]; c.w = v[7];
        *(short4*)&Ls[s][c8 * 8]     = a;
        *(short4*)&Ls[s][c8 * 8 + 4] = c;
    }
    __syncthreads();
    #pragma unroll
    for (int it = 0; it < 2; it++) {
        int d = (t >> 3) + it * 32, scol = t & 7;
        bf16x8 vv;
        #pragma unroll
        for (int j = 0; j < 8; j++) vv[j] = Ls[scol * 8 + j][d];
        *(bf16x8*)&VT[((long)bh * 64 + d) * 2048 + s0 + scol * 8] = vv;
    }
}

// ---------------------------------------------------------------------------
// m97-style bf16 MFMA GEMM (128x128 tile, BK=64, gll16 + XOR swizzle).
// oscale folds the attention scale * log2(e) into Q.
// ---------------------------------------------------------------------------
template <bool BF16_OUT>
__device__ __forceinline__ void gemm_core(
    const short* __restrict__ A, const short* __restrict__ Bw,
    const float* __restrict__ bias, void* __restrict__ outp,
    int r0, int n0, float oscale)
{
    __shared__ short As[128 * 64];
    __shared__ short Bs[128 * 64];

    const int t    = threadIdx.x;
    const int w    = t >> 6;
    const int ln   = t & 63;
    const int l15  = ln & 15;
    const int quad = ln >> 4;
    const int wr   = w >> 1;
    const int wc   = w & 1;

    f32x4 acc[4][4];
    #pragma unroll
    for (int i = 0; i < 4; i++)
        #pragma unroll
        for (int j = 0; j < 4; j++) acc[i][j] = (f32x4){0.f, 0.f, 0.f, 0.f};

    const int srow = ln >> 3;
    const int sc   = (ln & 7) ^ srow;
    const int rsw  = l15 & 7;

    for (int k0 = 0; k0 < 1024; k0 += 64) {
        __syncthreads();
        #pragma unroll
        for (int j = 0; j < 4; j++) {
            int q   = w * 4 + j;
            int row = q * 8 + srow;
            gll16(A  + ((long)(r0 + row) << 10) + k0 + sc * 8, As + q * 512);
            gll16(Bw + ((long)(n0 + row) << 10) + k0 + sc * 8, Bs + q * 512);
        }
        __syncthreads();
        #pragma unroll
        for (int kh = 0; kh < 2; kh++) {
            bf16x8 af[4], bfr[4];
            #pragma unroll
            for (int i = 0; i < 4; i++) {
                int ra = wr * 64 + i * 16 + l15;
                int rb = wc * 64 + i * 16 + l15;
                int pc = ((kh * 4 + quad) ^ rsw) * 8;
                af[i]  = *(const bf16x8*)&As[ra * 64 + pc];
                bfr[i] = *(const bf16x8*)&Bs[rb * 64 + pc];
            }
            #pragma unroll
            for (int i = 0; i < 4; i++)
                #pragma unroll
                for (int j = 0; j < 4; j++)
                    acc[i][j] = __builtin_amdgcn_mfma_f32_16x16x32_bf16(
                        af[i], bfr[j], acc[i][j], 0, 0, 0);
        }
    }

    #pragma unroll
    for (int j = 0; j < 4; j++) {
        int col = n0 + wc * 64 + j * 16 + l15;
        float bv = bias[col];
        #pragma unroll
        for (int i = 0; i < 4; i++) {
            int rowb = r0 + wr * 64 + i * 16 + quad * 4;
            #pragma unroll
            for (int r = 0; r < 4; r++) {
                float v = (acc[i][j][r] + bv) * oscale;
                if (BF16_OUT)
                    ((short*)outp)[(long)(rowb + r) * 1024 + col] = f2bf(v);
                else
                    ((float*)outp)[(long)(rowb + r) * 1024 + col] = v;
            }
        }
    }
}

// Q scale: 1/sqrt(64) * log2(e)  (flash uses raw v_exp_f32 = 2^x)
#define QSCALE 0.180336880977f

__global__ __launch_bounds__(256) void gemm_qkv_kernel(
    const short* __restrict__ x2b, const short* __restrict__ xb,
    const short* __restrict__ WqT, const short* __restrict__ WkT,
    const short* __restrict__ WvT,
    const float* __restrict__ bq, const float* __restrict__ bk,
    const float* __restrict__ bv,
    short* __restrict__ Qb, short* __restrict__ Kb, short* __restrict__ Vb)
{
    const int z = blockIdx.z;
    const short* A    = (z == 0) ? x2b : xb;
    const short* Bw   = (z == 0) ? WqT : (z == 1) ? WkT : WvT;
    const float* bias = (z == 0) ? bq  : (z == 1) ? bk  : bv;
    short* outp       = (z == 0) ? Qb  : (z == 1) ? Kb  : Vb;
    const float scl   = (z == 0) ? QSCALE : 1.0f;
    gemm_core<true>(A, Bw, bias, outp, blockIdx.x * 128, blockIdx.y * 128, scl);
}

__global__ __launch_bounds__(256) void gemm_out_kernel(
    const short* __restrict__ A, const short* __restrict__ Wob,
    const float* __restrict__ bo, float* __restrict__ out)
{
    gemm_core<false>(A, Wob, bo, out, blockIdx.x * 128, blockIdx.y * 128, 1.0f);
}

// ---------------------------------------------------------------------------
// MFMA flash attention v7 = R8 structure with two measured fixes:
//   (1) __builtin_amdgcn_exp2f (raw v_exp_f32) instead of libm exp2f
//   (2) Ps rows stride 72 shorts (144 B), PLAIN slot order: write bank =
//       (4*l15 + 2*slot) mod 32 -> full 32-bank coverage, 2-way max (free);
//       b128 read-back hits min-beat schedule. No XOR, no phys VALU.
// Block = 256 thr / 4 waves, 16 q/wave; grid (32,32)=1024 blocks (4/CU).
// K AND V staged via gll16 + XOR swizzle. S computed transposed (A=K, B=Q),
// P packed to one ds_write_b64 per kt. Static softmax; row-sum via ones-MFMA.
// Q,K bf16 [b,s,h*64+d]; VT bf16 [bh][64][2048]; O bf16 [b,s,1024].
// ---------------------------------------------------------------------------
__global__ __launch_bounds__(256) void flash_kernel(
    const short* __restrict__ Q, const short* __restrict__ K,
    const short* __restrict__ VT, short* __restrict__ O)
{
    const int t    = threadIdx.x;
    const int wave = t >> 6;
    const int ln   = t & 63;
    const int l15  = ln & 15;
    const int quad = ln >> 4;
    const int bh = blockIdx.y;
    const int b  = bh >> 4;
    const int h  = bh & 15;
    const int q0 = blockIdx.x * 64;
    const int wq = q0 + wave * 16;          // this wave's first q row

    __shared__ short Ks[64 * 64];           // [kpos][d], XOR-swizzled chunks
    __shared__ short Vs[64 * 64];           // [d][kpos], XOR-swizzled chunks
    __shared__ short Ps[4][16 * 72];        // per-wave P[q][kpos], stride-72 rows

    const int srow = ln >> 3;               // row within 8-row staging chunk
    const int sc   = (ln & 7) ^ srow;       // swizzled source chunk (16B)
    const int rsw  = l15 & 7;               // read-side swizzle key (K/V only)

    // Q B-fragments (pre-scaled by 0.125*log2e): lane l15 = q, k = quad*8+j
    bf16x8 aQ0, aQ1;
    {
        const short* Qp = Q + ((long)(b * SQ_ + wq + l15)) * 1024 + h * 64 + quad * 8;
        aQ0 = *(const bf16x8*)(Qp);
        aQ1 = *(const bf16x8*)(Qp + 32);
    }

    bf16x8 ones;
    #pragma unroll
    for (int j = 0; j < 8; j++) ones[j] = (short)0x3F80;   // bf16 1.0

    f32x4 o_acc[4];
    #pragma unroll
    for (int i = 0; i < 4; i++) o_acc[i] = (f32x4){0.f, 0.f, 0.f, 0.f};
    f32x4 l_acc = (f32x4){0.f, 0.f, 0.f, 0.f};

    const short* Kbase = K  + ((long)b * SK_) * 1024 + h * 64;
    const short* Vbase = VT + (long)bh * D_ * SK_;

    for (int k0 = 0; k0 < SK_; k0 += 64) {
        __syncthreads();                     // prev iter's frag reads done
        #pragma unroll
        for (int it = 0; it < 2; ++it) {
            int qq  = wave * 2 + it;         // 8-row group 0..7
            int row = qq * 8 + srow;         // kpos (K) / d (V)
            gll16(Kbase + (long)(k0 + row) * 1024 + sc * 8, Ks + qq * 512);
            gll16(Vbase + (long)row * 2048 + k0 + sc * 8,   Vs + qq * 512);
        }
        __syncthreads();                     // tiles staged

        // --- S^T[kpos][q] = K·Q^T : A = K frags from LDS, B = Q regs ---
        f32x4 st[4];
        #pragma unroll
        for (int kt = 0; kt < 4; kt++) {
            const short* kr = &Ks[(kt * 16 + l15) * 64];
            bf16x8 ka0 = *(const bf16x8*)&kr[((quad    ) ^ rsw) * 8];
            bf16x8 ka1 = *(const bf16x8*)&kr[((quad + 4) ^ rsw) * 8];
            f32x4 z = (f32x4){0.f, 0.f, 0.f, 0.f};
            z = __builtin_amdgcn_mfma_f32_16x16x32_bf16(ka0, aQ0, z, 0, 0, 0);
            z = __builtin_amdgcn_mfma_f32_16x16x32_bf16(ka1, aQ1, z, 0, 0, 0);
            st[kt] = z;
        }

        // --- P = 2^(S^T): lane q=l15, kpos=16kt+4quad+{0..3} ->
        //     one packed ds_write_b64 per kt, plain slot order ---
        short* pr = &Ps[wave][l15 * 72];
        #pragma unroll
        for (int kt = 0; kt < 4; kt++) {
            float p0 = __builtin_amdgcn_exp2f(st[kt][0]);
            float p1 = __builtin_amdgcn_exp2f(st[kt][1]);
            float p2 = __builtin_amdgcn_exp2f(st[kt][2]);
            float p3 = __builtin_amdgcn_exp2f(st[kt][3]);
            uint2 wv; wv.x = pk2bf(p0, p1); wv.y = pk2bf(p2, p3);
            *(uint2*)&pr[(4 * kt + quad) * 4] = wv;     // u64 slot 4kt+quad
        }

        // --- P A-frags (lane m=q=l15, k contiguous) ; l += P·1 ; O += P·V ---
        bf16x8 aP0 = *(const bf16x8*)&pr[quad * 8];
        bf16x8 aP1 = *(const bf16x8*)&pr[(quad + 4) * 8];
        l_acc = __builtin_amdgcn_mfma_f32_16x16x32_bf16(aP0, ones, l_acc, 0, 0, 0);
        l_acc = __builtin_amdgcn_mfma_f32_16x16x32_bf16(aP1, ones, l_acc, 0, 0, 0);
        #pragma unroll
        for (int dt = 0; dt < 4; dt++) {
            const short* vr = &Vs[(dt * 16 + l15) * 64];
            bf16x8 bv0 = *(const bf16x8*)&vr[((quad    ) ^ rsw) * 8];
            bf16x8 bv1 = *(const bf16x8*)&vr[((quad + 4) ^ rsw) * 8];
            o_acc[dt] = __builtin_amdgcn_mfma_f32_16x16x32_bf16(aP0, bv0, o_acc[dt], 0, 0, 0);
            o_acc[dt] = __builtin_amdgcn_mfma_f32_16x16x32_bf16(aP1, bv1, o_acc[dt], 0, 0, 0);
        }
    }

    // --- epilogue: normalize, write head-concat bf16 (col l15 = d) ---
    #pragma unroll
    for (int r = 0; r < 4; r++) {
        float inv = 1.0f / l_acc[r];
        long row = (long)b * SQ_ + wq + quad * 4 + r;
        short* Op = O + row * 1024 + h * 64 + l15;
        #pragma unroll
        for (int dt = 0; dt < 4; dt++)
            Op[dt * 16] = f2bf(o_acc[dt][r] * inv);
    }
}

extern "C" void kernel_launch(void* const* d_in, const int* in_sizes, int n_in,
                              void* d_out, int out_size, void* d_ws, size_t ws_size,
                              hipStream_t stream) {
    const float* x  = (const float*)d_in[0];
    const float* x2 = (const float*)d_in[1];
    const float* Wq = (const float*)d_in[2];
    const float* bq = (const float*)d_in[3];
    const float* Wk = (const float*)d_in[4];
    const float* bk = (const float*)d_in[5];
    const float* Wv = (const float*)d_in[6];
    const float* bv = (const float*)d_in[7];
    const float* Wo = (const float*)d_in[8];
    const float* bo = (const float*)d_in[9];
    float* out = (float*)d_out;

    const size_t nAct = (size_t)B_ * SK_ * DM_;    // 4,194,304
    const size_t nW   = (size_t)DM_ * DM_;         // 1,048,576
    short* bufA = (short*)d_ws;        // xb, later VT
    short* bufB = bufA + nAct;         // x2b, later O (bf16)
    short* Qb   = bufB + nAct;
    short* Kb   = Qb + nAct;
    short* Vb   = Kb + nAct;
    short* WqT  = Vb + nAct;
    short* WkT  = WqT + nW;
    short* WvT  = WkT + nW;
    short* Wob  = WvT + nW;

    prep_kernel<<<dim3(16, 16, 6), 256, 0, stream>>>(
        Wq, Wk, Wv, Wo, x, x2, WqT, WkT, WvT, Wob, bufA, bufB);

    gemm_qkv_kernel<<<dim3(32, 8, 3), 256, 0, stream>>>(
        bufB, bufA, WqT, WkT, WvT, bq, bk, bv, Qb, Kb, Vb);

    vtrans_kernel<<<dim3(32, 32), 256, 0, stream>>>(Vb, bufA);       // bufA = VT
    flash_kernel<<<dim3(32, 32), 256, 0, stream>>>(Qb, Kb, bufA, bufB); // bufB = O
    gemm_out_kernel<<<dim3(32, 8), 256, 0, stream>>>(bufB, Wob, bo, out);
}

// Round 10
// 223.778 us; speedup vs baseline: 1.4098x; 1.0326x over previous
//
#include <hip/hip_runtime.h>
#include <math.h>

#define B_   2
#define SQ_  2048
#define SK_  2048
#define DM_  1024
#define H_   16
#define D_   64

typedef __attribute__((ext_vector_type(8))) short bf16x8;
typedef __attribute__((ext_vector_type(4))) float f32x4;
typedef unsigned int u32;

// fp32 -> bf16 RNE
__device__ __forceinline__ short f2bf(float f) {
    union { float f; unsigned u; } v; v.f = f;
    unsigned r = v.u + 0x7FFFu + ((v.u >> 16) & 1u);
    return (short)(r >> 16);
}
// pack two fp32 -> two bf16 (round-half-up) in one u32
__device__ __forceinline__ u32 pk2bf(float x, float y) {
    union { float f; u32 u; } a, b; a.f = x; b.f = y;
    return ((a.u + 0x8000u) >> 16) | ((b.u + 0x8000u) & 0xFFFF0000u);
}

__device__ __forceinline__ void gll16(const void* g, void* l) {
    __builtin_amdgcn_global_load_lds(
        (const __attribute__((address_space(1))) u32*)g,
        (__attribute__((address_space(3))) u32*)l, 16, 0, 0);
}

// ---------------------------------------------------------------------------
// prep: z=0..2 -> Wq/Wk/Wv [16,1024,64] f32 -> WT[h*64+d][m] bf16 (transposed)
//       z=3    -> Wo fp32 -> bf16 convert
//       z=4,5  -> x / x2 fp32 -> bf16 convert
// ---------------------------------------------------------------------------
__global__ __launch_bounds__(256) void prep_kernel(
    const float* __restrict__ Wq, const float* __restrict__ Wk,
    const float* __restrict__ Wv, const float* __restrict__ Wo,
    const float* __restrict__ x,  const float* __restrict__ x2,
    short* __restrict__ WqT, short* __restrict__ WkT,
    short* __restrict__ WvT, short* __restrict__ Wob,
    short* __restrict__ xb,  short* __restrict__ x2b)
{
    const int t = threadIdx.x;
    const int z = blockIdx.z;
    if (z >= 3) {
        const float* src = (z == 3) ? Wo : (z == 4) ? x : x2;
        short* dst       = (z == 3) ? Wob : (z == 4) ? xb : x2b;
        int nloop = (z == 3) ? 4 : 16;              // Wo: 1M floats; x: 4M
        int bid = blockIdx.y * 16 + blockIdx.x;     // 0..255
        #pragma unroll 4
        for (int j = 0; j < nloop; j++) {
            int i = bid * (nloop * 256) + j * 256 + t;   // float4 units
            float4 v = ((const float4*)src)[i];
            short4 s;
            s.x = f2bf(v.x); s.y = f2bf(v.y); s.z = f2bf(v.z); s.w = f2bf(v.w);
            ((short4*)dst)[i] = s;
        }
        return;
    }
    const float* W = (z == 0) ? Wq : (z == 1) ? Wk : Wv;
    short* WT      = (z == 0) ? WqT : (z == 1) ? WkT : WvT;
    const int h  = blockIdx.y;
    const int m0 = blockIdx.x * 64;
    __shared__ short Ls[64][68];

    #pragma unroll
    for (int it = 0; it < 4; it++) {
        int lin = it * 256 + t;         // float4 units, 1024 total
        int m = lin >> 4, d4 = lin & 15;
        float4 v = *(const float4*)&W[((long)h * DM_ + m0 + m) * D_ + d4 * 4];
        short4 s;
        s.x = f2bf(v.x); s.y = f2bf(v.y); s.z = f2bf(v.z); s.w = f2bf(v.w);
        *(short4*)&Ls[m][d4 * 4] = s;
    }
    __syncthreads();
    #pragma unroll
    for (int it = 0; it < 2; it++) {
        int d = (t >> 3) + it * 32, scol = t & 7;
        bf16x8 vv;
        #pragma unroll
        for (int j = 0; j < 8; j++) vv[j] = Ls[scol * 8 + j][d];
        *(bf16x8*)&WT[((long)h * 64 + d) * DM_ + m0 + scol * 8] = vv;
    }
}

// ---------------------------------------------------------------------------
// m97-style bf16 MFMA GEMM, 128x128 tile, BK=64, gll16 + XOR swizzle.
// MODE 0: bf16 row-major out   MODE 1: fp32 row-major out
// MODE 2: bf16 out written directly in VT layout [bh][d][s] (fuses vtrans).
// oscale folds the attention scale * log2(e) into Q.
// ---------------------------------------------------------------------------
template <int MODE>
__device__ __forceinline__ void gemm_core(
    const short* __restrict__ A, const short* __restrict__ Bw,
    const float* __restrict__ bias, void* __restrict__ outp,
    int r0, int n0, float oscale)
{
    __shared__ short As[128 * 64];
    __shared__ short Bs[128 * 64];

    const int t    = threadIdx.x;
    const int w    = t >> 6;
    const int ln   = t & 63;
    const int l15  = ln & 15;
    const int quad = ln >> 4;
    const int wr   = w >> 1;
    const int wc   = w & 1;

    f32x4 acc[4][4];
    #pragma unroll
    for (int i = 0; i < 4; i++)
        #pragma unroll
        for (int j = 0; j < 4; j++) acc[i][j] = (f32x4){0.f, 0.f, 0.f, 0.f};

    const int srow = ln >> 3;
    const int sc   = (ln & 7) ^ srow;
    const int rsw  = l15 & 7;

    for (int k0 = 0; k0 < 1024; k0 += 64) {
        __syncthreads();
        #pragma unroll
        for (int j = 0; j < 4; j++) {
            int q   = w * 4 + j;
            int row = q * 8 + srow;
            gll16(A  + ((long)(r0 + row) << 10) + k0 + sc * 8, As + q * 512);
            gll16(Bw + ((long)(n0 + row) << 10) + k0 + sc * 8, Bs + q * 512);
        }
        __syncthreads();
        #pragma unroll
        for (int kh = 0; kh < 2; kh++) {
            bf16x8 af[4], bfr[4];
            #pragma unroll
            for (int i = 0; i < 4; i++) {
                int ra = wr * 64 + i * 16 + l15;
                int rb = wc * 64 + i * 16 + l15;
                int pc = ((kh * 4 + quad) ^ rsw) * 8;
                af[i]  = *(const bf16x8*)&As[ra * 64 + pc];
                bfr[i] = *(const bf16x8*)&Bs[rb * 64 + pc];
            }
            #pragma unroll
            for (int i = 0; i < 4; i++)
                #pragma unroll
                for (int j = 0; j < 4; j++)
                    acc[i][j] = __builtin_amdgcn_mfma_f32_16x16x32_bf16(
                        af[i], bfr[j], acc[i][j], 0, 0, 0);
        }
    }

    #pragma unroll
    for (int j = 0; j < 4; j++) {
        int col = n0 + wc * 64 + j * 16 + l15;
        float bv = bias[col];
        if (MODE == 2) {
            // VT[((b*16+h)*64 + d)][s], 4 consecutive s per lane (short4)
            int hh = col >> 6, dd = col & 63;
            #pragma unroll
            for (int i = 0; i < 4; i++) {
                int rowb = r0 + wr * 64 + i * 16 + quad * 4;
                int bb = rowb >> 11, ss = rowb & 2047;
                short4 sv;
                sv.x = f2bf(acc[i][j][0] + bv);
                sv.y = f2bf(acc[i][j][1] + bv);
                sv.z = f2bf(acc[i][j][2] + bv);
                sv.w = f2bf(acc[i][j][3] + bv);
                *(short4*)&((short*)outp)[
                    ((long)(((bb << 4) + hh) * 64 + dd) << 11) + ss] = sv;
            }
        } else {
            #pragma unroll
            for (int i = 0; i < 4; i++) {
                int rowb = r0 + wr * 64 + i * 16 + quad * 4;
                #pragma unroll
                for (int r = 0; r < 4; r++) {
                    float v = (acc[i][j][r] + bv) * oscale;
                    if (MODE == 0)
                        ((short*)outp)[(long)(rowb + r) * 1024 + col] = f2bf(v);
                    else
                        ((float*)outp)[(long)(rowb + r) * 1024 + col] = v;
                }
            }
        }
    }
}

// Q scale: 1/sqrt(64) * log2(e)  (flash uses raw v_exp_f32 = 2^x)
#define QSCALE 0.180336880977f

__global__ __launch_bounds__(256) void gemm_qkv_kernel(
    const short* __restrict__ x2b, const short* __restrict__ xb,
    const short* __restrict__ WqT, const short* __restrict__ WkT,
    const short* __restrict__ WvT,
    const float* __restrict__ bq, const float* __restrict__ bk,
    const float* __restrict__ bv,
    short* __restrict__ Qb, short* __restrict__ Kb, short* __restrict__ VT)
{
    const int z = blockIdx.z;
    if (z == 0) {
        gemm_core<0>(x2b, WqT, bq, Qb, blockIdx.x * 128, blockIdx.y * 128, QSCALE);
    } else if (z == 1) {
        gemm_core<0>(xb, WkT, bk, Kb, blockIdx.x * 128, blockIdx.y * 128, 1.0f);
    } else {
        gemm_core<2>(xb, WvT, bv, VT, blockIdx.x * 128, blockIdx.y * 128, 1.0f);
    }
}

// ---------------------------------------------------------------------------
// gemm_out: 64x128 tiles -> grid (64,8) = 512 blocks = 2 blocks/CU
// (128x128 gave only 256 blocks = 1/CU: zero cross-block latency hiding).
// 4 waves in 2x2: each wave 32 rows x 64 cols (acc 2x4).
// ---------------------------------------------------------------------------
__global__ __launch_bounds__(256) void gemm_out_kernel(
    const short* __restrict__ A, const short* __restrict__ Bw,
    const float* __restrict__ bias, float* __restrict__ outp)
{
    __shared__ short As[64 * 64];
    __shared__ short Bs[128 * 64];

    const int r0   = blockIdx.x * 64;
    const int n0   = blockIdx.y * 128;
    const int t    = threadIdx.x;
    const int w    = t >> 6;
    const int ln   = t & 63;
    const int l15  = ln & 15;
    const int quad = ln >> 4;
    const int wr   = w >> 1;            // row group (32 rows)
    const int wc   = w & 1;             // col group (64 cols)

    f32x4 acc[2][4];
    #pragma unroll
    for (int i = 0; i < 2; i++)
        #pragma unroll
        for (int j = 0; j < 4; j++) acc[i][j] = (f32x4){0.f, 0.f, 0.f, 0.f};

    const int srow = ln >> 3;
    const int sc   = (ln & 7) ^ srow;
    const int rsw  = l15 & 7;

    for (int k0 = 0; k0 < 1024; k0 += 64) {
        __syncthreads();
        #pragma unroll
        for (int j = 0; j < 6; j++) {           // 24 issues: 8 A + 16 B
            int q = w * 6 + j;
            if (q < 8) {
                int row = q * 8 + srow;
                gll16(A + ((long)(r0 + row) << 10) + k0 + sc * 8, As + q * 512);
            } else {
                int qb = q - 8;
                int row = qb * 8 + srow;
                gll16(Bw + ((long)(n0 + row) << 10) + k0 + sc * 8, Bs + qb * 512);
            }
        }
        __syncthreads();
        #pragma unroll
        for (int kh = 0; kh < 2; kh++) {
            int pc = ((kh * 4 + quad) ^ rsw) * 8;
            bf16x8 af[2], bfr[4];
            #pragma unroll
            for (int i = 0; i < 2; i++)
                af[i] = *(const bf16x8*)&As[(wr * 32 + i * 16 + l15) * 64 + pc];
            #pragma unroll
            for (int j = 0; j < 4; j++)
                bfr[j] = *(const bf16x8*)&Bs[(wc * 64 + j * 16 + l15) * 64 + pc];
            #pragma unroll
            for (int i = 0; i < 2; i++)
                #pragma unroll
                for (int j = 0; j < 4; j++)
                    acc[i][j] = __builtin_amdgcn_mfma_f32_16x16x32_bf16(
                        af[i], bfr[j], acc[i][j], 0, 0, 0);
        }
    }

    #pragma unroll
    for (int j = 0; j < 4; j++) {
        int col = n0 + wc * 64 + j * 16 + l15;
        float bv = bias[col];
        #pragma unroll
        for (int i = 0; i < 2; i++) {
            int rowb = r0 + wr * 32 + i * 16 + quad * 4;
            #pragma unroll
            for (int r = 0; r < 4; r++)
                outp[(long)(rowb + r) * 1024 + col] = acc[i][j][r] + bv;
        }
    }
}

// ---------------------------------------------------------------------------
// MFMA flash attention (R9, verified 68.2 us — unchanged).
// ---------------------------------------------------------------------------
__global__ __launch_bounds__(256) void flash_kernel(
    const short* __restrict__ Q, const short* __restrict__ K,
    const short* __restrict__ VT, short* __restrict__ O)
{
    const int t    = threadIdx.x;
    const int wave = t >> 6;
    const int ln   = t & 63;
    const int l15  = ln & 15;
    const int quad = ln >> 4;
    const int bh = blockIdx.y;
    const int b  = bh >> 4;
    const int h  = bh & 15;
    const int q0 = blockIdx.x * 64;
    const int wq = q0 + wave * 16;          // this wave's first q row

    __shared__ short Ks[64 * 64];           // [kpos][d], XOR-swizzled chunks
    __shared__ short Vs[64 * 64];           // [d][kpos], XOR-swizzled chunks
    __shared__ short Ps[4][16 * 72];        // per-wave P[q][kpos], stride-72 rows

    const int srow = ln >> 3;               // row within 8-row staging chunk
    const int sc   = (ln & 7) ^ srow;       // swizzled source chunk (16B)
    const int rsw  = l15 & 7;               // read-side swizzle key (K/V only)

    // Q B-fragments (pre-scaled by 0.125*log2e): lane l15 = q, k = quad*8+j
    bf16x8 aQ0, aQ1;
    {
        const short* Qp = Q + ((long)(b * SQ_ + wq + l15)) * 1024 + h * 64 + quad * 8;
        aQ0 = *(const bf16x8*)(Qp);
        aQ1 = *(const bf16x8*)(Qp + 32);
    }

    bf16x8 ones;
    #pragma unroll
    for (int j = 0; j < 8; j++) ones[j] = (short)0x3F80;   // bf16 1.0

    f32x4 o_acc[4];
    #pragma unroll
    for (int i = 0; i < 4; i++) o_acc[i] = (f32x4){0.f, 0.f, 0.f, 0.f};
    f32x4 l_acc = (f32x4){0.f, 0.f, 0.f, 0.f};

    const short* Kbase = K  + ((long)b * SK_) * 1024 + h * 64;
    const short* Vbase = VT + (long)bh * D_ * SK_;

    for (int k0 = 0; k0 < SK_; k0 += 64) {
        __syncthreads();                     // prev iter's frag reads done
        #pragma unroll
        for (int it = 0; it < 2; ++it) {
            int qq  = wave * 2 + it;         // 8-row group 0..7
            int row = qq * 8 + srow;         // kpos (K) / d (V)
            gll16(Kbase + (long)(k0 + row) * 1024 + sc * 8, Ks + qq * 512);
            gll16(Vbase + (long)row * 2048 + k0 + sc * 8,   Vs + qq * 512);
        }
        __syncthreads();                     // tiles staged

        // --- S^T[kpos][q] = K·Q^T : A = K frags from LDS, B = Q regs ---
        f32x4 st[4];
        #pragma unroll
        for (int kt = 0; kt < 4; kt++) {
            const short* kr = &Ks[(kt * 16 + l15) * 64];
            bf16x8 ka0 = *(const bf16x8*)&kr[((quad    ) ^ rsw) * 8];
            bf16x8 ka1 = *(const bf16x8*)&kr[((quad + 4) ^ rsw) * 8];
            f32x4 z = (f32x4){0.f, 0.f, 0.f, 0.f};
            z = __builtin_amdgcn_mfma_f32_16x16x32_bf16(ka0, aQ0, z, 0, 0, 0);
            z = __builtin_amdgcn_mfma_f32_16x16x32_bf16(ka1, aQ1, z, 0, 0, 0);
            st[kt] = z;
        }

        // --- P = 2^(S^T): lane q=l15, kpos=16kt+4quad+{0..3} ->
        //     one packed ds_write_b64 per kt, plain slot order ---
        short* pr = &Ps[wave][l15 * 72];
        #pragma unroll
        for (int kt = 0; kt < 4; kt++) {
            float p0 = __builtin_amdgcn_exp2f(st[kt][0]);
            float p1 = __builtin_amdgcn_exp2f(st[kt][1]);
            float p2 = __builtin_amdgcn_exp2f(st[kt][2]);
            float p3 = __builtin_amdgcn_exp2f(st[kt][3]);
            uint2 wv; wv.x = pk2bf(p0, p1); wv.y = pk2bf(p2, p3);
            *(uint2*)&pr[(4 * kt + quad) * 4] = wv;     // u64 slot 4kt+quad
        }

        // --- P A-frags (lane m=q=l15, k contiguous) ; l += P·1 ; O += P·V ---
        bf16x8 aP0 = *(const bf16x8*)&pr[quad * 8];
        bf16x8 aP1 = *(const bf16x8*)&pr[(quad + 4) * 8];
        l_acc = __builtin_amdgcn_mfma_f32_16x16x32_bf16(aP0, ones, l_acc, 0, 0, 0);
        l_acc = __builtin_amdgcn_mfma_f32_16x16x32_bf16(aP1, ones, l_acc, 0, 0, 0);
        #pragma unroll
        for (int dt = 0; dt < 4; dt++) {
            const short* vr = &Vs[(dt * 16 + l15) * 64];
            bf16x8 bv0 = *(const bf16x8*)&vr[((quad    ) ^ rsw) * 8];
            bf16x8 bv1 = *(const bf16x8*)&vr[((quad + 4) ^ rsw) * 8];
            o_acc[dt] = __builtin_amdgcn_mfma_f32_16x16x32_bf16(aP0, bv0, o_acc[dt], 0, 0, 0);
            o_acc[dt] = __builtin_amdgcn_mfma_f32_16x16x32_bf16(aP1, bv1, o_acc[dt], 0, 0, 0);
        }
    }

    // --- epilogue: normalize, write head-concat bf16 (col l15 = d) ---
    #pragma unroll
    for (int r = 0; r < 4; r++) {
        float inv = 1.0f / l_acc[r];
        long row = (long)b * SQ_ + wq + quad * 4 + r;
        short* Op = O + row * 1024 + h * 64 + l15;
        #pragma unroll
        for (int dt = 0; dt < 4; dt++)
            Op[dt * 16] = f2bf(o_acc[dt][r] * inv);
    }
}

extern "C" void kernel_launch(void* const* d_in, const int* in_sizes, int n_in,
                              void* d_out, int out_size, void* d_ws, size_t ws_size,
                              hipStream_t stream) {
    const float* x  = (const float*)d_in[0];
    const float* x2 = (const float*)d_in[1];
    const float* Wq = (const float*)d_in[2];
    const float* bq = (const float*)d_in[3];
    const float* Wk = (const float*)d_in[4];
    const float* bk = (const float*)d_in[5];
    const float* Wv = (const float*)d_in[6];
    const float* bv = (const float*)d_in[7];
    const float* Wo = (const float*)d_in[8];
    const float* bo = (const float*)d_in[9];
    float* out = (float*)d_out;

    const size_t nAct = (size_t)B_ * SK_ * DM_;    // 4,194,304
    const size_t nW   = (size_t)DM_ * DM_;         // 1,048,576
    short* bufA = (short*)d_ws;        // xb
    short* bufB = bufA + nAct;         // x2b, later O (bf16)
    short* Qb   = bufB + nAct;
    short* Kb   = Qb + nAct;
    short* VTws = Kb + nAct;           // V written directly in VT layout
    short* WqT  = VTws + nAct;
    short* WkT  = WqT + nW;
    short* WvT  = WkT + nW;
    short* Wob  = WvT + nW;
    // total 5*nAct + 4*nW shorts = 50 MiB

    prep_kernel<<<dim3(16, 16, 6), 256, 0, stream>>>(
        Wq, Wk, Wv, Wo, x, x2, WqT, WkT, WvT, Wob, bufA, bufB);

    gemm_qkv_kernel<<<dim3(32, 8, 3), 256, 0, stream>>>(
        bufB, bufA, WqT, WkT, WvT, bq, bk, bv, Qb, Kb, VTws);

    flash_kernel<<<dim3(32, 32), 256, 0, stream>>>(Qb, Kb, VTws, bufB); // bufB = O
    gemm_out_kernel<<<dim3(64, 8), 256, 0, stream>>>(bufB, Wob, bo, out);
}